// Round 1
// baseline (90.227 us; speedup 1.0000x reference)
//
#include <hip/hip_runtime.h>
#include <hip/hip_bf16.h>
#include <stdint.h>

#define N_NODES 4096
#define BATCH 2

// ---------------------------------------------------------------------------
// 1. Row-normalize embeddings: ne[i] = emb[i] / ||emb[i]||   (4096 x 64)
// ---------------------------------------------------------------------------
__global__ __launch_bounds__(64) void norm_kernel(const float* __restrict__ emb,
                                                  float* __restrict__ ne) {
    int row = blockIdx.x;
    int l = threadIdx.x;
    float v = emb[row * 64 + l];
    float s = v * v;
#pragma unroll
    for (int m = 32; m >= 1; m >>= 1) s += __shfl_xor(s, m);
    ne[row * 64 + l] = v / sqrtf(s);
}

// ---------------------------------------------------------------------------
// 2. Adjacency bitmask: mask[i][w] = bits j=w*64..w*64+63 of (ne_i . ne_j > 0.5)
//    64x64 output tile per block; 4 waves x 16 rows; 4-row register tiling.
//    LDS tiles stored with 16B-block XOR swizzle -> conflict-free ds_read_b128.
// ---------------------------------------------------------------------------
#define SWZ(row, k4) (((row) * 64) + ((((k4) ^ ((row) & 15))) << 2))

__global__ __launch_bounds__(256) void adj_kernel(const float* __restrict__ ne,
                                                  unsigned long long* __restrict__ mask) {
    __shared__ float At[64 * 64];
    __shared__ float Bt[64 * 64];
    int t = threadIdx.x;
    int ti = blockIdx.y, tj = blockIdx.x;

    // load tiles (each thread: 4x float4)
    int r = t >> 4;            // 0..15
    int c4 = t & 15;           // float4 column block 0..15
#pragma unroll
    for (int p = 0; p < 4; ++p) {
        int row = p * 16 + r;
        float4 a = *(const float4*)&ne[(size_t)(ti * 64 + row) * 64 + c4 * 4];
        float4 b = *(const float4*)&ne[(size_t)(tj * 64 + row) * 64 + c4 * 4];
        *(float4*)&At[SWZ(row, c4)] = a;
        *(float4*)&Bt[SWZ(row, c4)] = b;
    }
    __syncthreads();

    int w = t >> 6;   // wave 0..3
    int l = t & 63;   // lane = j within tile
#pragma unroll
    for (int g = 0; g < 4; ++g) {
        int i0 = w * 16 + g * 4;
        float acc0 = 0.f, acc1 = 0.f, acc2 = 0.f, acc3 = 0.f;
#pragma unroll
        for (int k4 = 0; k4 < 16; ++k4) {
            float4 bv = *(const float4*)&Bt[SWZ(l, k4)];
            float4 a0 = *(const float4*)&At[SWZ(i0 + 0, k4)];
            float4 a1 = *(const float4*)&At[SWZ(i0 + 1, k4)];
            float4 a2 = *(const float4*)&At[SWZ(i0 + 2, k4)];
            float4 a3 = *(const float4*)&At[SWZ(i0 + 3, k4)];
            acc0 += a0.x * bv.x + a0.y * bv.y + a0.z * bv.z + a0.w * bv.w;
            acc1 += a1.x * bv.x + a1.y * bv.y + a1.z * bv.z + a1.w * bv.w;
            acc2 += a2.x * bv.x + a2.y * bv.y + a2.z * bv.z + a2.w * bv.w;
            acc3 += a3.x * bv.x + a3.y * bv.y + a3.z * bv.z + a3.w * bv.w;
        }
        unsigned long long m0 = __ballot(acc0 > 0.5f);
        unsigned long long m1 = __ballot(acc1 > 0.5f);
        unsigned long long m2 = __ballot(acc2 > 0.5f);
        unsigned long long m3 = __ballot(acc3 > 0.5f);
        if (l == 0) {
            mask[(size_t)(ti * 64 + i0 + 0) * 64 + tj] = m0;
            mask[(size_t)(ti * 64 + i0 + 1) * 64 + tj] = m1;
            mask[(size_t)(ti * 64 + i0 + 2) * 64 + tj] = m2;
            mask[(size_t)(ti * 64 + i0 + 3) * 64 + tj] = m3;
        }
    }
}

// ---------------------------------------------------------------------------
// 3. h0 = x @ W_proj + b_proj   ([8192,16] @ [16,64])
// ---------------------------------------------------------------------------
__global__ __launch_bounds__(256) void proj_kernel(const float* __restrict__ x,
                                                   const float* __restrict__ W,
                                                   const float* __restrict__ bias,
                                                   float* __restrict__ h0) {
    int row = blockIdx.x * 4 + (threadIdx.x >> 6);
    int l = threadIdx.x & 63;
    const float* xr = x + (size_t)row * 16;
    float acc = bias[l];
#pragma unroll
    for (int k = 0; k < 16; ++k) acc += xr[k] * W[k * 64 + l];
    h0[(size_t)row * 64 + l] = acc;
}

// ---------------------------------------------------------------------------
// 4. Fused per-row matmul + per-head attention scores.
//    hout[row,t] = sum_k hin[row,k]*W[k,t];  s_{src,dst}[row,h] = <hout_h, a_h>
// ---------------------------------------------------------------------------
template <int HIN, int HOUT, int F>
__global__ __launch_bounds__(64) void mm_scores_kernel(
        const float* __restrict__ hin, const float* __restrict__ W,
        const float* __restrict__ asrc, const float* __restrict__ adst,
        float* __restrict__ hout, float* __restrict__ ssrc, float* __restrict__ sdst) {
    int row = blockIdx.x;
    int t = threadIdx.x;
    const float* hr = hin + (size_t)row * HIN;
    if (t < HOUT) {
        float acc = 0.f;
#pragma unroll
        for (int k = 0; k < HIN; ++k) acc += hr[k] * W[k * HOUT + t];
        hout[(size_t)row * HOUT + t] = acc;
        float ps = acc * asrc[t];
        float pd = acc * adst[t];
#pragma unroll
        for (int m = F / 2; m >= 1; m >>= 1) {
            ps += __shfl_xor(ps, m);
            pd += __shfl_xor(pd, m);
        }
        if ((t & (F - 1)) == 0) {
            ssrc[(size_t)row * 4 + t / F] = ps;
            sdst[(size_t)row * 4 + t / F] = pd;
        }
    }
}

// ---------------------------------------------------------------------------
// 5. GAT aggregation, one wave per output row, online softmax over set bits.
//    out[row,t] = sum_j alpha[j] * h[j,t] + bias[t]   (optional ReLU)
// ---------------------------------------------------------------------------
template <int HID, int F, int RELU>
__global__ __launch_bounds__(64) void gat_agg_kernel(
        const float* __restrict__ hfeat, const float* __restrict__ ssrc,
        const float* __restrict__ sdst, const unsigned long long* __restrict__ mask,
        const float* __restrict__ bias, float* __restrict__ out) {
    int row = blockIdx.x;            // b*N + i
    int i = row & (N_NODES - 1);
    int bN = row - i;                // batch offset in rows
    int t = threadIdx.x;
    int tt = t & (HID - 1);
    int hh = tt / F;

    float sd = sdst[(size_t)row * 4 + hh];
    unsigned long long myword = mask[(size_t)i * 64 + t];

    float m = -1e30f, denom = 0.f, acc = 0.f;
    unsigned long long nz = __ballot(myword != 0ULL);
    while (nz) {
        int l = __ffsll(nz) - 1;
        nz &= nz - 1;
        unsigned long long wbits = __shfl(myword, l);
        while (wbits) {
            int bpos = __ffsll(wbits) - 1;
            wbits &= wbits - 1;
            int j = (l << 6) + bpos;
            float e = sd + ssrc[(size_t)(bN + j) * 4 + hh];
            e = e > 0.f ? e : 0.2f * e;            // LeakyReLU(0.2)
            float mn = fmaxf(m, e);
            float cf = __expf(m - mn);             // rescale old state
            float wg = __expf(e - mn);
            float hv = hfeat[(size_t)(bN + j) * HID + tt];
            denom = denom * cf + wg;
            acc = acc * cf + wg * hv;
            m = mn;
        }
    }
    float o = acc / denom + bias[tt];
    if (RELU) o = fmaxf(o, 0.f);
    if (t < HID) out[(size_t)row * HID + tt] = o;
}

// ---------------------------------------------------------------------------
extern "C" void kernel_launch(void* const* d_in, const int* in_sizes, int n_in,
                              void* d_out, int out_size, void* d_ws, size_t ws_size,
                              hipStream_t stream) {
    const float* x   = (const float*)d_in[0];
    const float* emb = (const float*)d_in[1];
    const float* Wp  = (const float*)d_in[2];
    const float* bp  = (const float*)d_in[3];
    const float* W1  = (const float*)d_in[4];
    const float* a1s = (const float*)d_in[5];
    const float* a1d = (const float*)d_in[6];
    const float* b1  = (const float*)d_in[7];
    const float* W2  = (const float*)d_in[8];
    const float* a2s = (const float*)d_in[9];
    const float* a2d = (const float*)d_in[10];
    const float* b2  = (const float*)d_in[11];

    const int ROWS = BATCH * N_NODES;  // 8192

    char* w = (char*)d_ws;
    float* ne = (float*)w;                        w += (size_t)N_NODES * 64 * 4;
    unsigned long long* mask = (unsigned long long*)w; w += (size_t)N_NODES * 64 * 8;
    float* h0  = (float*)w;                       w += (size_t)ROWS * 64 * 4;
    float* h1  = (float*)w;                       w += (size_t)ROWS * 64 * 4;
    float* s1s = (float*)w;                       w += (size_t)ROWS * 4 * 4;
    float* s1d = (float*)w;                       w += (size_t)ROWS * 4 * 4;
    float* out1 = (float*)w;                      w += (size_t)ROWS * 64 * 4;
    float* h2  = (float*)w;                       w += (size_t)ROWS * 32 * 4;
    float* s2s = (float*)w;                       w += (size_t)ROWS * 4 * 4;
    float* s2d = (float*)w;                       w += (size_t)ROWS * 4 * 4;

    norm_kernel<<<dim3(N_NODES), dim3(64), 0, stream>>>(emb, ne);
    adj_kernel<<<dim3(64, 64), dim3(256), 0, stream>>>(ne, mask);
    proj_kernel<<<dim3(ROWS / 4), dim3(256), 0, stream>>>(x, Wp, bp, h0);
    mm_scores_kernel<64, 64, 16><<<dim3(ROWS), dim3(64), 0, stream>>>(
        h0, W1, a1s, a1d, h1, s1s, s1d);
    gat_agg_kernel<64, 16, 1><<<dim3(ROWS), dim3(64), 0, stream>>>(
        h1, s1s, s1d, mask, b1, out1);
    mm_scores_kernel<64, 32, 8><<<dim3(ROWS), dim3(64), 0, stream>>>(
        out1, W2, a2s, a2d, h2, s2s, s2d);
    gat_agg_kernel<32, 8, 0><<<dim3(ROWS), dim3(64), 0, stream>>>(
        h2, s2s, s2d, mask, b2, (float*)d_out);
}

// Round 2
// 76.327 us; speedup vs baseline: 1.1821x; 1.1821x over previous
//
#include <hip/hip_runtime.h>
#include <hip/hip_bf16.h>
#include <stdint.h>

#define N_NODES 4096
#define BATCH 2

typedef __attribute__((ext_vector_type(8))) short short8v;
typedef __attribute__((ext_vector_type(4))) float f32x4;

// round-to-nearest-even float -> bf16 bits (finite inputs only)
static __device__ inline unsigned short f2bf_rn(float x) {
    unsigned u = __float_as_uint(x);
    unsigned r = (u + 0x7FFFu + ((u >> 16) & 1u)) >> 16;
    return (unsigned short)r;
}
static __device__ inline float bf2f(unsigned short b) {
    return __uint_as_float(((unsigned)b) << 16);
}

// ---------------------------------------------------------------------------
// 1. Row-normalize embeddings, emit split-bf16: ne = hi + lo (each bf16)
// ---------------------------------------------------------------------------
__global__ __launch_bounds__(64) void norm_kernel(const float* __restrict__ emb,
                                                  unsigned short* __restrict__ hi,
                                                  unsigned short* __restrict__ lo) {
    int row = blockIdx.x;
    int l = threadIdx.x;
    float v = emb[row * 64 + l];
    float s = v * v;
#pragma unroll
    for (int m = 32; m >= 1; m >>= 1) s += __shfl_xor(s, m);
    float nv = v / sqrtf(s);
    unsigned short h = f2bf_rn(nv);
    unsigned short lw = f2bf_rn(nv - bf2f(h));
    hi[row * 64 + l] = h;
    lo[row * 64 + l] = lw;
}

// ---------------------------------------------------------------------------
// 2. Adjacency bitmask via split-bf16 MFMA.
//    Block = 4 waves; wave w computes rows i0..i0+15 (i0 = blockIdx.y*64+w*16)
//    against j-word blockIdx.x (64 cols) -> 16 mask words.
//    dot = aH.bH + aH.bL + aL.bH + aL.bL  (fp32 MFMA accum), err ~3e-7.
// ---------------------------------------------------------------------------
__global__ __launch_bounds__(256) void adj_mfma_kernel(
        const unsigned short* __restrict__ hi, const unsigned short* __restrict__ lo,
        unsigned long long* __restrict__ mask) {
    int t = threadIdx.x;
    int wave = t >> 6, l = t & 63;
    int jw = blockIdx.x;                 // j-word index (64 cols)
    int i0 = blockIdx.y * 64 + wave * 16;
    int fr = l & 15;                     // fragment row (i or j within tile)
    int koff = (l >> 4) * 8;             // k offset within 32-wide k-block

    const unsigned short* arow_hi = hi + (size_t)(i0 + fr) * 64 + koff;
    const unsigned short* arow_lo = lo + (size_t)(i0 + fr) * 64 + koff;
    short8v aH0 = *(const short8v*)(arow_hi);
    short8v aH1 = *(const short8v*)(arow_hi + 32);
    short8v aL0 = *(const short8v*)(arow_lo);
    short8v aL1 = *(const short8v*)(arow_lo + 32);

    int lr = l & 15;
    int shift = (lr >> 2) * 16;
    int r = l & 3;
    unsigned long long w64 = 0;

#pragma unroll
    for (int js = 0; js < 4; ++js) {
        int j0 = jw * 64 + js * 16;
        const unsigned short* brow_hi = hi + (size_t)(j0 + fr) * 64 + koff;
        const unsigned short* brow_lo = lo + (size_t)(j0 + fr) * 64 + koff;
        short8v bH0 = *(const short8v*)(brow_hi);
        short8v bH1 = *(const short8v*)(brow_hi + 32);
        short8v bL0 = *(const short8v*)(brow_lo);
        short8v bL1 = *(const short8v*)(brow_lo + 32);

        f32x4 acc = {0.f, 0.f, 0.f, 0.f};
        acc = __builtin_amdgcn_mfma_f32_16x16x32_bf16(aH0, bH0, acc, 0, 0, 0);
        acc = __builtin_amdgcn_mfma_f32_16x16x32_bf16(aH1, bH1, acc, 0, 0, 0);
        acc = __builtin_amdgcn_mfma_f32_16x16x32_bf16(aH0, bL0, acc, 0, 0, 0);
        acc = __builtin_amdgcn_mfma_f32_16x16x32_bf16(aH1, bL1, acc, 0, 0, 0);
        acc = __builtin_amdgcn_mfma_f32_16x16x32_bf16(aL0, bH0, acc, 0, 0, 0);
        acc = __builtin_amdgcn_mfma_f32_16x16x32_bf16(aL1, bH1, acc, 0, 0, 0);
        acc = __builtin_amdgcn_mfma_f32_16x16x32_bf16(aL0, bL0, acc, 0, 0, 0);
        acc = __builtin_amdgcn_mfma_f32_16x16x32_bf16(aL1, bL1, acc, 0, 0, 0);

        // C/D layout (m89-verified): col = lane&15, row = (lane>>4)*4 + reg.
        unsigned long long b0 = __ballot(acc[0] > 0.5f);
        unsigned long long b1 = __ballot(acc[1] > 0.5f);
        unsigned long long b2 = __ballot(acc[2] > 0.5f);
        unsigned long long b3 = __ballot(acc[3] > 0.5f);
        // lane lr (<16) assembles row lr: reg = lr&3, lane-group = lr>>2.
        unsigned long long sel = r == 0 ? b0 : r == 1 ? b1 : r == 2 ? b2 : b3;
        w64 |= ((sel >> shift) & 0xFFFFULL) << (js * 16);
    }
    if (l < 16) mask[(size_t)(i0 + l) * 64 + jw] = w64;
}

// ---------------------------------------------------------------------------
// 3. h0 = x @ W_proj + b_proj   ([8192,16] @ [16,64])
// ---------------------------------------------------------------------------
__global__ __launch_bounds__(256) void proj_kernel(const float* __restrict__ x,
                                                   const float* __restrict__ W,
                                                   const float* __restrict__ bias,
                                                   float* __restrict__ h0) {
    int row = blockIdx.x * 4 + (threadIdx.x >> 6);
    int l = threadIdx.x & 63;
    const float* xr = x + (size_t)row * 16;
    float acc = bias[l];
#pragma unroll
    for (int k = 0; k < 16; ++k) acc += xr[k] * W[k * 64 + l];
    h0[(size_t)row * 64 + l] = acc;
}

// ---------------------------------------------------------------------------
// 4. Fused per-row matmul + per-head attention scores.
// ---------------------------------------------------------------------------
template <int HIN, int HOUT, int F>
__global__ __launch_bounds__(64) void mm_scores_kernel(
        const float* __restrict__ hin, const float* __restrict__ W,
        const float* __restrict__ asrc, const float* __restrict__ adst,
        float* __restrict__ hout, float* __restrict__ ssrc, float* __restrict__ sdst) {
    int row = blockIdx.x;
    int t = threadIdx.x;
    const float* hr = hin + (size_t)row * HIN;
    if (t < HOUT) {
        float acc = 0.f;
#pragma unroll
        for (int k = 0; k < HIN; ++k) acc += hr[k] * W[k * HOUT + t];
        hout[(size_t)row * HOUT + t] = acc;
        float ps = acc * asrc[t];
        float pd = acc * adst[t];
#pragma unroll
        for (int m = F / 2; m >= 1; m >>= 1) {
            ps += __shfl_xor(ps, m);
            pd += __shfl_xor(pd, m);
        }
        if ((t & (F - 1)) == 0) {
            ssrc[(size_t)row * 4 + t / F] = ps;
            sdst[(size_t)row * 4 + t / F] = pd;
        }
    }
}

// ---------------------------------------------------------------------------
// 5. GAT aggregation, one wave per output row, online softmax over set bits.
// ---------------------------------------------------------------------------
template <int HID, int F, int RELU>
__global__ __launch_bounds__(64) void gat_agg_kernel(
        const float* __restrict__ hfeat, const float* __restrict__ ssrc,
        const float* __restrict__ sdst, const unsigned long long* __restrict__ mask,
        const float* __restrict__ bias, float* __restrict__ out) {
    int row = blockIdx.x;            // b*N + i
    int i = row & (N_NODES - 1);
    int bN = row - i;                // batch offset in rows
    int t = threadIdx.x;
    int tt = t & (HID - 1);
    int hh = tt / F;

    float sd = sdst[(size_t)row * 4 + hh];
    unsigned long long myword = mask[(size_t)i * 64 + t];

    float m = -1e30f, denom = 0.f, acc = 0.f;
    unsigned long long nz = __ballot(myword != 0ULL);
    while (nz) {
        int l = __ffsll(nz) - 1;
        nz &= nz - 1;
        unsigned long long wbits = __shfl(myword, l);
        while (wbits) {
            int bpos = __ffsll(wbits) - 1;
            wbits &= wbits - 1;
            int j = (l << 6) + bpos;
            float e = sd + ssrc[(size_t)(bN + j) * 4 + hh];
            e = e > 0.f ? e : 0.2f * e;            // LeakyReLU(0.2)
            float mn = fmaxf(m, e);
            float cf = __expf(m - mn);             // rescale old state
            float wg = __expf(e - mn);
            float hv = hfeat[(size_t)(bN + j) * HID + tt];
            denom = denom * cf + wg;
            acc = acc * cf + wg * hv;
            m = mn;
        }
    }
    float o = acc / denom + bias[tt];
    if (RELU) o = fmaxf(o, 0.f);
    if (t < HID) out[(size_t)row * HID + tt] = o;
}

// ---------------------------------------------------------------------------
extern "C" void kernel_launch(void* const* d_in, const int* in_sizes, int n_in,
                              void* d_out, int out_size, void* d_ws, size_t ws_size,
                              hipStream_t stream) {
    const float* x   = (const float*)d_in[0];
    const float* emb = (const float*)d_in[1];
    const float* Wp  = (const float*)d_in[2];
    const float* bp  = (const float*)d_in[3];
    const float* W1  = (const float*)d_in[4];
    const float* a1s = (const float*)d_in[5];
    const float* a1d = (const float*)d_in[6];
    const float* b1  = (const float*)d_in[7];
    const float* W2  = (const float*)d_in[8];
    const float* a2s = (const float*)d_in[9];
    const float* a2d = (const float*)d_in[10];
    const float* b2  = (const float*)d_in[11];

    const int ROWS = BATCH * N_NODES;  // 8192

    char* w = (char*)d_ws;
    unsigned short* ne_hi = (unsigned short*)w;  w += (size_t)N_NODES * 64 * 2;
    unsigned short* ne_lo = (unsigned short*)w;  w += (size_t)N_NODES * 64 * 2;
    unsigned long long* mask = (unsigned long long*)w; w += (size_t)N_NODES * 64 * 8;
    float* h0  = (float*)w;                      w += (size_t)ROWS * 64 * 4;
    float* h1  = (float*)w;                      w += (size_t)ROWS * 64 * 4;
    float* s1s = (float*)w;                      w += (size_t)ROWS * 4 * 4;
    float* s1d = (float*)w;                      w += (size_t)ROWS * 4 * 4;
    float* out1 = (float*)w;                     w += (size_t)ROWS * 64 * 4;
    float* h2  = (float*)w;                      w += (size_t)ROWS * 32 * 4;
    float* s2s = (float*)w;                      w += (size_t)ROWS * 4 * 4;
    float* s2d = (float*)w;                      w += (size_t)ROWS * 4 * 4;

    norm_kernel<<<dim3(N_NODES), dim3(64), 0, stream>>>(emb, ne_hi, ne_lo);
    adj_mfma_kernel<<<dim3(64, 64), dim3(256), 0, stream>>>(ne_hi, ne_lo, mask);
    proj_kernel<<<dim3(ROWS / 4), dim3(256), 0, stream>>>(x, Wp, bp, h0);
    mm_scores_kernel<64, 64, 16><<<dim3(ROWS), dim3(64), 0, stream>>>(
        h0, W1, a1s, a1d, h1, s1s, s1d);
    gat_agg_kernel<64, 16, 1><<<dim3(ROWS), dim3(64), 0, stream>>>(
        h1, s1s, s1d, mask, b1, out1);
    mm_scores_kernel<64, 32, 8><<<dim3(ROWS), dim3(64), 0, stream>>>(
        out1, W2, a2s, a2d, h2, s2s, s2d);
    gat_agg_kernel<32, 8, 0><<<dim3(ROWS), dim3(64), 0, stream>>>(
        h2, s2s, s2d, mask, b2, (float*)d_out);
}

// Round 3
// 39.060 us; speedup vs baseline: 2.3100x; 1.9541x over previous
//
#include <hip/hip_runtime.h>
#include <hip/hip_bf16.h>
#include <stdint.h>

#define N_NODES 4096
#define BATCH 2

typedef __attribute__((ext_vector_type(8))) short short8v;
typedef __attribute__((ext_vector_type(4))) float f32x4;

#define GLL16(gsrc, ldst) \
    __builtin_amdgcn_global_load_lds((const __attribute__((address_space(1))) void*)(gsrc), \
                                     (__attribute__((address_space(3))) void*)(ldst), 16, 0, 0)

static __device__ inline unsigned short f2bf_rn(float x) {
    unsigned u = __float_as_uint(x);
    unsigned r = (u + 0x7FFFu + ((u >> 16) & 1u)) >> 16;
    return (unsigned short)r;
}
static __device__ inline float bf2f(unsigned short b) {
    return __uint_as_float(((unsigned)b) << 16);
}
static __device__ inline float rl(float v, int k) {   // wave-uniform broadcast
    return __uint_as_float(__builtin_amdgcn_readlane(__float_as_uint(v), k));
}

// ---------------------------------------------------------------------------
// 1. Row-normalize embeddings, emit split-bf16: ne = hi + lo (each bf16)
// ---------------------------------------------------------------------------
__global__ __launch_bounds__(64) void norm_kernel(const float* __restrict__ emb,
                                                  unsigned short* __restrict__ hi,
                                                  unsigned short* __restrict__ lo) {
    int row = blockIdx.x;
    int l = threadIdx.x;
    float v = emb[row * 64 + l];
    float s = v * v;
#pragma unroll
    for (int m = 32; m >= 1; m >>= 1) s += __shfl_xor(s, m);
    float nv = v / sqrtf(s);
    unsigned short h = f2bf_rn(nv);
    unsigned short lw = f2bf_rn(nv - bf2f(h));
    hi[row * 64 + l] = h;
    lo[row * 64 + l] = lw;
}

// ---------------------------------------------------------------------------
// 2. Adjacency bitmask: 128x128 tile/block, LDS-staged split-bf16 MFMA GEMM.
//    LDS holds XOR-swizzled tiles (slot c holds global slot c^(row&7)) staged
//    via global_load_lds with pre-swizzled global source (linear LDS dest).
//    dot = aH.bH + aH.bL + aL.bH  (lo.lo dropped, ~5e-7)
// ---------------------------------------------------------------------------
__global__ __launch_bounds__(256) void adj_mfma_kernel(
        const unsigned short* __restrict__ hi, const unsigned short* __restrict__ lo,
        unsigned long long* __restrict__ mask) {
    __shared__ unsigned short Ah[128 * 64];
    __shared__ unsigned short Al[128 * 64];
    __shared__ unsigned short Bh[128 * 64];
    __shared__ unsigned short Bl[128 * 64];
    int t = threadIdx.x;
    int w = t >> 6, l = t & 63;
    int i0 = blockIdx.y * 128, j0 = blockIdx.x * 128;

    // ---- stage: wave w stages local rows [w*32, w*32+32) of each buffer ----
    int cr = l >> 3;                 // row within 8-row chunk
    int slot = (l & 7) ^ cr;         // pre-swizzled source 16B-slot
#pragma unroll
    for (int q = 0; q < 4; ++q) {
        int lr = w * 32 + q * 8;     // local chunk base row
        size_t ga = (size_t)(i0 + lr + cr) * 64 + slot * 8;
        size_t gb = (size_t)(j0 + lr + cr) * 64 + slot * 8;
        GLL16(hi + ga, &Ah[lr * 64]);
        GLL16(lo + ga, &Al[lr * 64]);
        GLL16(hi + gb, &Bh[lr * 64]);
        GLL16(lo + gb, &Bl[lr * 64]);
    }
    __syncthreads();

    // ---- A fragments for this wave's 2 row-tiles (rows w*32 .. w*32+32) ----
    int fr = l & 15;
    int s0 = l >> 4;                 // k-slot 0..3 (k = slot*8 .. +8)
    int r7 = l & 7;                  // == (local row) & 7 for all tiles
    short8v aH[2][2], aL[2][2];
#pragma unroll
    for (int rt = 0; rt < 2; ++rt) {
        int base = (w * 32 + rt * 16 + fr) * 64;
        aH[rt][0] = *(const short8v*)&Ah[base + ((s0 ^ r7) << 3)];
        aH[rt][1] = *(const short8v*)&Ah[base + (((s0 + 4) ^ r7) << 3)];
        aL[rt][0] = *(const short8v*)&Al[base + ((s0 ^ r7) << 3)];
        aL[rt][1] = *(const short8v*)&Al[base + (((s0 + 4) ^ r7) << 3)];
    }

    f32x4 acc[2][8];
#pragma unroll
    for (int rt = 0; rt < 2; ++rt)
#pragma unroll
        for (int js = 0; js < 8; ++js) acc[rt][js] = (f32x4){0.f, 0.f, 0.f, 0.f};

#pragma unroll
    for (int js = 0; js < 8; ++js) {
        int bbase = (js * 16 + fr) * 64;
        short8v bH0 = *(const short8v*)&Bh[bbase + ((s0 ^ r7) << 3)];
        short8v bH1 = *(const short8v*)&Bh[bbase + (((s0 + 4) ^ r7) << 3)];
        short8v bL0 = *(const short8v*)&Bl[bbase + ((s0 ^ r7) << 3)];
        short8v bL1 = *(const short8v*)&Bl[bbase + (((s0 + 4) ^ r7) << 3)];
#pragma unroll
        for (int rt = 0; rt < 2; ++rt) {
            f32x4 a = acc[rt][js];
            a = __builtin_amdgcn_mfma_f32_16x16x32_bf16(aH[rt][0], bH0, a, 0, 0, 0);
            a = __builtin_amdgcn_mfma_f32_16x16x32_bf16(aH[rt][1], bH1, a, 0, 0, 0);
            a = __builtin_amdgcn_mfma_f32_16x16x32_bf16(aH[rt][0], bL0, a, 0, 0, 0);
            a = __builtin_amdgcn_mfma_f32_16x16x32_bf16(aH[rt][1], bL1, a, 0, 0, 0);
            a = __builtin_amdgcn_mfma_f32_16x16x32_bf16(aL[rt][0], bH0, a, 0, 0, 0);
            a = __builtin_amdgcn_mfma_f32_16x16x32_bf16(aL[rt][1], bH1, a, 0, 0, 0);
            acc[rt][js] = a;
        }
    }

    // ---- pack to bitmask. C/D layout: col=lane&15, row=(lane>>4)*4+reg ----
    int shift = ((l & 15) >> 2) * 16;
    int r = l & 3;
#pragma unroll
    for (int rt = 0; rt < 2; ++rt) {
#pragma unroll
        for (int ws_ = 0; ws_ < 2; ++ws_) {
            unsigned long long w64 = 0;
#pragma unroll
            for (int js2 = 0; js2 < 4; ++js2) {
                f32x4 a = acc[rt][ws_ * 4 + js2];
                unsigned long long b0 = __ballot(a[0] > 0.5f);
                unsigned long long b1 = __ballot(a[1] > 0.5f);
                unsigned long long b2 = __ballot(a[2] > 0.5f);
                unsigned long long b3 = __ballot(a[3] > 0.5f);
                unsigned long long sel = r == 0 ? b0 : r == 1 ? b1 : r == 2 ? b2 : b3;
                w64 |= ((sel >> shift) & 0xFFFFULL) << (js2 * 16);
            }
            if (l < 16)
                mask[(size_t)(i0 + w * 32 + rt * 16 + l) * 64 + blockIdx.x * 2 + ws_] = w64;
        }
    }
}

// ---------------------------------------------------------------------------
// 3. Fused: h0 = x@Wp + bp; h1 = h0@W1; scores1. 4 rows per wave (readlane
//    broadcast), so Wp/W1 are loaded once per 4 rows.
// ---------------------------------------------------------------------------
__global__ __launch_bounds__(256) void feat1_kernel(
        const float* __restrict__ x, const float* __restrict__ Wp,
        const float* __restrict__ bp, const float* __restrict__ W1,
        const float* __restrict__ a1s, const float* __restrict__ a1d,
        float* __restrict__ h1out, float* __restrict__ ssrc, float* __restrict__ sdst) {
    int w = threadIdx.x >> 6, l = threadIdx.x & 63;
    int row0 = blockIdx.x * 16 + w * 4;

    float xv[4];
#pragma unroll
    for (int r = 0; r < 4; ++r) xv[r] = x[(size_t)(row0 + r) * 16 + (l & 15)];

    float h0[4];
    float bpv = bp[l];
#pragma unroll
    for (int r = 0; r < 4; ++r) h0[r] = bpv;
#pragma unroll
    for (int k = 0; k < 16; ++k) {
        float wk = Wp[k * 64 + l];
#pragma unroll
        for (int r = 0; r < 4; ++r) h0[r] += rl(xv[r], k) * wk;
    }

    float h1[4] = {0.f, 0.f, 0.f, 0.f};
#pragma unroll
    for (int k = 0; k < 64; ++k) {
        float wk = W1[k * 64 + l];
#pragma unroll
        for (int r = 0; r < 4; ++r) h1[r] += rl(h0[r], k) * wk;
    }

    float as_ = a1s[l], ad_ = a1d[l];
#pragma unroll
    for (int r = 0; r < 4; ++r) {
        h1out[(size_t)(row0 + r) * 64 + l] = h1[r];
        float ps = h1[r] * as_, pd = h1[r] * ad_;
#pragma unroll
        for (int m = 8; m >= 1; m >>= 1) {
            ps += __shfl_xor(ps, m);
            pd += __shfl_xor(pd, m);
        }
        if ((l & 15) == 0) {
            ssrc[(size_t)(row0 + r) * 4 + (l >> 4)] = ps;
            sdst[(size_t)(row0 + r) * 4 + (l >> 4)] = pd;
        }
    }
}

// ---------------------------------------------------------------------------
// 4. Fused GAT-1 aggregation (+bias+ReLU) + mm2 (h2 = out1@W2) + scores2.
//    One wave per row; online softmax over set mask bits.
// ---------------------------------------------------------------------------
__global__ __launch_bounds__(64) void agg1_fused_kernel(
        const float* __restrict__ h1, const float* __restrict__ ssrc,
        const float* __restrict__ sdst, const unsigned long long* __restrict__ mask,
        const float* __restrict__ b1, const float* __restrict__ W2,
        const float* __restrict__ a2s, const float* __restrict__ a2d,
        float* __restrict__ h2out, float* __restrict__ s2s, float* __restrict__ s2d) {
    int row = blockIdx.x;
    int i = row & (N_NODES - 1);
    int bN = row - i;
    int t = threadIdx.x;
    int hh = t >> 4;

    float sd = sdst[(size_t)row * 4 + hh];
    unsigned long long myword = mask[(size_t)i * 64 + t];

    float m = -1e30f, denom = 0.f, acc = 0.f;
    unsigned long long nz = __ballot(myword != 0ULL);
    while (nz) {
        int lw = __ffsll(nz) - 1;
        nz &= nz - 1;
        unsigned long long wbits = __shfl(myword, lw);
        while (wbits) {
            int bpos = __ffsll(wbits) - 1;
            wbits &= wbits - 1;
            int j = (lw << 6) + bpos;
            float e = sd + ssrc[(size_t)(bN + j) * 4 + hh];
            e = e > 0.f ? e : 0.2f * e;
            float mn = fmaxf(m, e);
            float cf = __expf(m - mn);
            float wg = __expf(e - mn);
            float hv = h1[(size_t)(bN + j) * 64 + t];
            denom = denom * cf + wg;
            acc = acc * cf + wg * hv;
            m = mn;
        }
    }
    float o = fmaxf(acc / denom + b1[t], 0.f);   // out1 row, lane t = feature t

    // mm2: h2[t'] = sum_k o_k * W2[k*32+t']  (lanes 32..63 duplicate 0..31)
    int l2 = t & 31;
    float acc2 = 0.f;
#pragma unroll
    for (int k = 0; k < 64; ++k) acc2 += rl(o, k) * W2[k * 32 + l2];

    float ps = acc2 * a2s[l2], pd = acc2 * a2d[l2];
#pragma unroll
    for (int mm = 4; mm >= 1; mm >>= 1) {
        ps += __shfl_xor(ps, mm);
        pd += __shfl_xor(pd, mm);
    }
    if (t < 32) {
        h2out[(size_t)row * 32 + t] = acc2;
        if ((t & 7) == 0) {
            s2s[(size_t)row * 4 + (t >> 3)] = ps;
            s2d[(size_t)row * 4 + (t >> 3)] = pd;
        }
    }
}

// ---------------------------------------------------------------------------
// 5. GAT-2 aggregation -> d_out
// ---------------------------------------------------------------------------
template <int HID, int F, int RELU>
__global__ __launch_bounds__(64) void gat_agg_kernel(
        const float* __restrict__ hfeat, const float* __restrict__ ssrc,
        const float* __restrict__ sdst, const unsigned long long* __restrict__ mask,
        const float* __restrict__ bias, float* __restrict__ out) {
    int row = blockIdx.x;
    int i = row & (N_NODES - 1);
    int bN = row - i;
    int t = threadIdx.x;
    int tt = t & (HID - 1);
    int hh = tt / F;

    float sd = sdst[(size_t)row * 4 + hh];
    unsigned long long myword = mask[(size_t)i * 64 + t];

    float m = -1e30f, denom = 0.f, acc = 0.f;
    unsigned long long nz = __ballot(myword != 0ULL);
    while (nz) {
        int lw = __ffsll(nz) - 1;
        nz &= nz - 1;
        unsigned long long wbits = __shfl(myword, lw);
        while (wbits) {
            int bpos = __ffsll(wbits) - 1;
            wbits &= wbits - 1;
            int j = (lw << 6) + bpos;
            float e = sd + ssrc[(size_t)(bN + j) * 4 + hh];
            e = e > 0.f ? e : 0.2f * e;
            float mn = fmaxf(m, e);
            float cf = __expf(m - mn);
            float wg = __expf(e - mn);
            float hv = hfeat[(size_t)(bN + j) * HID + tt];
            denom = denom * cf + wg;
            acc = acc * cf + wg * hv;
            m = mn;
        }
    }
    float o = acc / denom + bias[tt];
    if (RELU) o = fmaxf(o, 0.f);
    if (t < HID) out[(size_t)row * HID + tt] = o;
}

// ---------------------------------------------------------------------------
extern "C" void kernel_launch(void* const* d_in, const int* in_sizes, int n_in,
                              void* d_out, int out_size, void* d_ws, size_t ws_size,
                              hipStream_t stream) {
    const float* x   = (const float*)d_in[0];
    const float* emb = (const float*)d_in[1];
    const float* Wp  = (const float*)d_in[2];
    const float* bp  = (const float*)d_in[3];
    const float* W1  = (const float*)d_in[4];
    const float* a1s = (const float*)d_in[5];
    const float* a1d = (const float*)d_in[6];
    const float* b1  = (const float*)d_in[7];
    const float* W2  = (const float*)d_in[8];
    const float* a2s = (const float*)d_in[9];
    const float* a2d = (const float*)d_in[10];
    const float* b2  = (const float*)d_in[11];

    const int ROWS = BATCH * N_NODES;  // 8192

    char* w = (char*)d_ws;
    unsigned short* ne_hi = (unsigned short*)w;  w += (size_t)N_NODES * 64 * 2;
    unsigned short* ne_lo = (unsigned short*)w;  w += (size_t)N_NODES * 64 * 2;
    unsigned long long* mask = (unsigned long long*)w; w += (size_t)N_NODES * 64 * 8;
    float* h1  = (float*)w;                      w += (size_t)ROWS * 64 * 4;
    float* s1s = (float*)w;                      w += (size_t)ROWS * 4 * 4;
    float* s1d = (float*)w;                      w += (size_t)ROWS * 4 * 4;
    float* h2  = (float*)w;                      w += (size_t)ROWS * 32 * 4;
    float* s2s = (float*)w;                      w += (size_t)ROWS * 4 * 4;
    float* s2d = (float*)w;                      w += (size_t)ROWS * 4 * 4;

    norm_kernel<<<dim3(N_NODES), dim3(64), 0, stream>>>(emb, ne_hi, ne_lo);
    adj_mfma_kernel<<<dim3(32, 32), dim3(256), 0, stream>>>(ne_hi, ne_lo, mask);
    feat1_kernel<<<dim3(ROWS / 16), dim3(256), 0, stream>>>(
        x, Wp, bp, W1, a1s, a1d, h1, s1s, s1d);
    agg1_fused_kernel<<<dim3(ROWS), dim3(64), 0, stream>>>(
        h1, s1s, s1d, mask, b1, W2, a2s, a2d, h2, s2s, s2d);
    gat_agg_kernel<32, 8, 0><<<dim3(ROWS), dim3(64), 0, stream>>>(
        h2, s2s, s2d, mask, b2, (float*)d_out);
}